// Round 9
// baseline (230.016 us; speedup 1.0000x reference)
//
#include <hip/hip_runtime.h>

// Problem constants: B=2, S=2048, D=1024, H=16, HD=64
#define S_LEN 2048
#define NH 16
#define HD 64
#define DMODEL 1024

typedef __bf16 bf16x8 __attribute__((ext_vector_type(8)));
typedef float floatx4 __attribute__((ext_vector_type(4)));
typedef short short8 __attribute__((ext_vector_type(8)));

__device__ inline unsigned short f2bf(float f) {
    union { float f; unsigned u; } v; v.f = f;
    unsigned u = v.u;
    unsigned r = (u + 0x7FFFu + ((u >> 16) & 1u)) >> 16;  // RNE
    return (unsigned short)r;
}

__device__ __forceinline__ void gload_lds16(const void* g, void* l) {
    __builtin_amdgcn_global_load_lds(
        (const __attribute__((address_space(1))) unsigned int*)g,
        (__attribute__((address_space(3))) unsigned int*)l, 16, 0, 0);
}

// ---------------------------------------------------------------------------
// K0: prepass. fp32 -> bf16 for x, w_qkv, w_proj (RNE), and cos/sin table.
// ---------------------------------------------------------------------------
__device__ __forceinline__ void cvt4(const float4* __restrict__ src,
                                     uint2* __restrict__ dst, int i) {
    float4 v = src[i];
    union { unsigned short u[4]; uint2 d; } o;
    o.u[0] = f2bf(v.x); o.u[1] = f2bf(v.y); o.u[2] = f2bf(v.z); o.u[3] = f2bf(v.w);
    dst[i] = o.d;
}

__global__ __launch_bounds__(256) void prep_kernel(
    const float* __restrict__ x, const float* __restrict__ wq,
    const float* __restrict__ wp, const float* __restrict__ freqs,
    unsigned short* __restrict__ xb, unsigned short* __restrict__ wqb,
    unsigned short* __restrict__ wpb, float2* __restrict__ cs)
{
    const int tid = blockIdx.x * 256 + threadIdx.x;
    const int nth = gridDim.x * 256;
    for (int i = tid; i < (4096 * 1024) / 4; i += nth) cvt4((const float4*)x, (uint2*)xb, i);
    for (int i = tid; i < (3072 * 1024) / 4; i += nth) cvt4((const float4*)wq, (uint2*)wqb, i);
    for (int i = tid; i < (1024 * 1024) / 4; i += nth) cvt4((const float4*)wp, (uint2*)wpb, i);
    for (int i = tid; i < S_LEN * 32; i += nth) {
        const float f = freqs[i];
        float2 c; c.x = cosf(f); c.y = sinf(f);
        cs[i] = c;
    }
}

// Bank swizzle for 32-col (4x16B-chunk) row-major LDS tiles (A tile only now).
#define SROW(r) (((r) & 3) ^ (((r) >> 2) & 3))

// ---------------------------------------------------------------------------
// K1: qkv = x_bf16 @ w_qkv_bf16^T + b_qkv, fused RoPE (table) + scatter.
// 128x128 tile, 4 waves, BK=32. NEW (R9): B IS NOT STAGED IN LDS.
// Diagnosis: per K-step per CU the old scheme issued 96 ds_read_b128
// (~1150 cyc of LDS pipe) vs 233 cyc of MFMA -> LDS-read-BW-bound; every
// schedule variant (R3/R4/R5) was identical because the drain never mattered.
// Fix: B fragments (16-row x 32-k global blocks, L2-hot weights) are loaded
// straight into registers, double-buffered one K-step ahead; A keeps the
// proven gload_lds double-buffer. LDS reads/wave/step: 8 -> 4.
// LDS: 18KB (A dbuf 16KB, epilogue Vt reuses 18KB). ~145 VGPR, 3 blocks/CU.
//  q -> [bh][s][hd] row-major, PRE-SCALED by 1/sqrt(HD)=0.125 (exact)
//  k -> blocked [bh][hdblk(8)][s(2048)][8]   (RoPE applied)
//  v -> blocked [bh][sblk(256)][hd(64)][8]   (transposed via LDS tile)
// ---------------------------------------------------------------------------
#define QKV_STAGE(dA, kk) do { \
    gload_lds16(ag + (kk),               (dA) + wv * 512); \
    gload_lds16(ag + 64 * DMODEL + (kk), (dA) + 2048 + wv * 512); \
} while (0)

#define QKV_BLOAD(BF, kk) do { \
    _Pragma("unroll") for (int n_ = 0; n_ < 4; n_++) \
        (BF)[n_] = *(const bf16x8*)(bqb + (size_t)n_ * 16 * DMODEL + (kk)); \
} while (0)

#define QKV_COMPUTE(sA, BF) do { \
    bf16x8 af[4]; \
    _Pragma("unroll") for (int m_ = 0; m_ < 4; m_++) af[m_] = *(const bf16x8*)&(sA)[aoff[m_]]; \
    _Pragma("unroll") for (int n_ = 0; n_ < 4; n_++) { \
        _Pragma("unroll") for (int m_ = 0; m_ < 4; m_++) \
            acc[m_][n_] = __builtin_amdgcn_mfma_f32_16x16x32_bf16(af[m_], (BF)[n_], acc[m_][n_], 0, 0, 0); \
    } \
} while (0)

__global__ __launch_bounds__(256, 3) void qkv_gemm_kernel(
    const unsigned short* __restrict__ xb, const unsigned short* __restrict__ wqb,
    const float* __restrict__ bias, const float2* __restrict__ cs,
    unsigned short* __restrict__ qb, unsigned short* __restrict__ kb,
    unsigned short* __restrict__ vb)
{
    // A dbuf: A0 = smem, A1 = smem+4096 (shorts). Epilogue Vt reuses 9216.
    __shared__ __align__(16) unsigned short smem[9216];
    unsigned short* A0 = smem;
    unsigned short* A1 = smem + 4096;

    const int t = threadIdx.x;
    const int v = (blockIdx.x & 7) * 96 + (blockIdx.x >> 3);   // XCD swizzle
    const int mbase = (v / 24) * 128;   // 32 m-tiles
    const int nbase = (v % 24) * 128;   // 24 n-tiles
    const int wv = t >> 6, lane = t & 63;
    const int quad = lane >> 4, l16 = lane & 15;
    const int wr = wv >> 1, wc = wv & 1;

    floatx4 acc[4][4];
    #pragma unroll
    for (int m = 0; m < 4; m++)
        #pragma unroll
        for (int n = 0; n < 4; n++)
            #pragma unroll
            for (int r = 0; r < 4; r++) acc[m][n][r] = 0.f;

    // A staging: thread t owns LDS 16B slot t (row t>>2, chunk t&3); source
    // chunk pre-swizzled so slot (row,c) holds global chunk c^SROW(row).
    const int srow = t >> 2;
    const int schunk = (t & 3) ^ SROW(srow);
    const unsigned short* ag = xb + (size_t)(mbase + srow) * DMODEL + schunk * 8;

    // B fragments direct from global (L2-hot): lane (quad,l16) of frag n holds
    // B[nbase + wc*64 + n*16 + l16][k0 + quad*8 .. +8] — the exact MFMA
    // B-operand layout the LDS path used to deliver.
    const unsigned short* bqb = wqb + (size_t)(nbase + wc * 64 + l16) * DMODEL + quad * 8;

    const int Sl = SROW(l16);
    int aoff[4];
    #pragma unroll
    for (int m = 0; m < 4; m++) aoff[m] = (wr * 64 + m * 16 + l16) * 32 + (quad ^ Sl) * 8;

    bf16x8 bfc[4], bfn[4];
    QKV_STAGE(A0, 0);
    QKV_BLOAD(bfc, 0);
    __syncthreads();                       // drains vmcnt -> A0 + bfc ready
    for (int k0 = 0; k0 < DMODEL; k0 += 64) {
        QKV_STAGE(A1, k0 + 32);            // next A tile in flight
        QKV_BLOAD(bfn, k0 + 32);           // next B frags in flight
        QKV_COMPUTE(A0, bfc);              // latency hidden under compute
        __syncthreads();                   // A1 + bfn landed; A0 free
        if (k0 + 64 < DMODEL) {
            QKV_STAGE(A0, k0 + 64);
            QKV_BLOAD(bfc, k0 + 64);
        }
        QKV_COMPUTE(A1, bfn);
        __syncthreads();
    }

    const int part = nbase >> 10;                 // 0=q 1=k 2=v
    const int bidx = mbase >> 11;
    const int s0   = mbase & 2047;

    if (part == 2) {
        unsigned short* Vt = smem;                // 128 hd x 72 s-pad (9216)
        const int hb = (nbase & 1023) >> 6;
        float bvv[4];
        #pragma unroll
        for (int nt = 0; nt < 4; nt++) bvv[nt] = bias[nbase + wc * 64 + nt * 16 + l16];
        #pragma unroll
        for (int shalf = 0; shalf < 2; shalf++) {
            __syncthreads();
            if (wr == shalf) {
                #pragma unroll
                for (int nt = 0; nt < 4; nt++) {
                    const int hdl = wc * 64 + nt * 16 + l16;
                    #pragma unroll
                    for (int m = 0; m < 4; m++)
                        #pragma unroll
                        for (int r = 0; r < 4; r++)
                            Vt[hdl * 72 + m * 16 + quad * 4 + r] = f2bf(acc[m][nt][r] + bvv[nt]);
                }
            }
            __syncthreads();
            const int hdl = t & 127, sp = t >> 7;
            const size_t bh2 = (size_t)bidx * NH + hb + (hdl >> 6);
            #pragma unroll
            for (int c = 0; c < 4; c++) {
                const int sl0 = (sp * 4 + c) * 8;
                const int sg = s0 + shalf * 64 + sl0;
                short8 vv = *(const short8*)&Vt[hdl * 72 + sl0];
                *(short8*)&vb[((bh2 * 256 + (sg >> 3)) * 64 + (hdl & 63)) * 8] = vv;
            }
        }
    } else {
        const size_t bhb = (size_t)bidx * NH;
        const int odd = l16 & 1;
        #pragma unroll
        for (int nt = 0; nt < 4; nt++) {
            const int n_ = nbase + wc * 64 + nt * 16 + l16;
            const int hd = n_ & 63;
            const size_t bh = bhb + ((n_ & 1023) >> 6);
            const float bvv = bias[n_];
            const int ci = (nt * 16 + l16) >> 1;
            #pragma unroll
            for (int m = 0; m < 4; m++) {
                #pragma unroll
                for (int r = 0; r < 4; r++) {
                    const int s = s0 + wr * 64 + m * 16 + quad * 4 + r;
                    float val = acc[m][nt][r] + bvv;
                    float other = __shfl_xor(val, 1, 64);
                    const float2 csv = cs[(size_t)s * 32 + ci];
                    float outv = odd ? fmaf(other, csv.y, val * csv.x)
                                     : fmaf(-other, csv.y, val * csv.x);
                    if (part == 0) {
                        qb[(bh * S_LEN + s) * HD + hd] = f2bf(outv * 0.125f);
                    } else {
                        kb[((bh * 8 + (hd >> 3)) * (size_t)S_LEN + s) * 8 + (hd & 7)] = f2bf(outv);
                    }
                }
            }
        }
    }
}

// ---------------------------------------------------------------------------
// K2: causal flash attention (R8: QBLK=128, 512 threads, 8 waves, 2-phase
// dbuf staging, reversed launch, setprio). Unchanged.
// ---------------------------------------------------------------------------
__global__ __launch_bounds__(512, 4) void attn_kernel(
    const unsigned short* __restrict__ qb, const unsigned short* __restrict__ kb,
    const unsigned short* __restrict__ vbk, unsigned short* __restrict__ ao)
{
    __shared__ __align__(16) unsigned short Ks[2][8 * 512];
    __shared__ __align__(16) unsigned short Vt[2][8 * 512];
    __shared__ __align__(16) unsigned short Pw[8][16 * 72];

    const int t = threadIdx.x;
    const int wv = t >> 6, lane = t & 63, quad = lane >> 4, l16 = lane & 15;
    const int qp = 15 - (blockIdx.x >> 5);        // reversed: long blocks first
    const int qbase = qp * 128;
    const int bhid = blockIdx.x & 31;
    const int h = bhid & 15, b = bhid >> 4;
    const size_t bh = (size_t)b * NH + h;
    const unsigned short* qg  = qb + bh * S_LEN * HD;
    const unsigned short* kgB = kb + bh * 8 * S_LEN * 8;
    const unsigned short* vgB = vbk + bh * 256 * 64 * 8;

    bf16x8 qf[2];
    {
        const unsigned short* q0 = qg + (size_t)(qbase + wv * 16 + l16) * HD;
        qf[0] = *(const bf16x8*)&q0[quad * 8];
        qf[1] = *(const bf16x8*)&q0[32 + quad * 8];
    }

    bf16x8 ones;
    {
        union { short8 s; bf16x8 v; } o;
        for (int j = 0; j < 8; j++) o.s[j] = 0x3F80;
        ones = o.v;
    }

    floatx4 lfr = {0.f, 0.f, 0.f, 0.f};
    floatx4 Ofr[4];
    for (int nt = 0; nt < 4; nt++)
        for (int r = 0; r < 4; r++) Ofr[nt][r] = 0.f;

    const int ntiles = (qbase >> 6) + 2;          // covers q rows qbase..qbase+127

#define ATTN_STAGE(bufi, kt_) do { \
    const int kb_ = (kt_) * 64; \
    const unsigned short* g0 = kgB + ((size_t)wv * S_LEN + kb_ + lane) * 8; \
    gload_lds16(g0, &Ks[bufi][wv * 512]); \
    const unsigned short* g1 = vgB + ((size_t)((kb_ >> 3) + wv) * 64 + lane) * 8; \
    gload_lds16(g1, &Vt[bufi][wv * 512]); \
} while (0)

#define ATTN_COMPUTE(bufi, kt_) do { \
    const int kbase = (kt_) * 64; \
    float pex[4][4]; \
    __builtin_amdgcn_s_setprio(1); \
    _Pragma("unroll") for (int sub = 0; sub < 4; sub++) { \
        bf16x8 kf0 = *(const bf16x8*)&Ks[bufi][(0 * 4 + quad) * 512 + (sub * 16 + l16) * 8]; \
        bf16x8 kf1 = *(const bf16x8*)&Ks[bufi][(1 * 4 + quad) * 512 + (sub * 16 + l16) * 8]; \
        floatx4 sacc = {0.f, 0.f, 0.f, 0.f}; \
        sacc = __builtin_amdgcn_mfma_f32_16x16x32_bf16(kf0, qf[0], sacc, 0, 0, 0); \
        sacc = __builtin_amdgcn_mfma_f32_16x16x32_bf16(kf1, qf[1], sacc, 0, 0, 0); \
        _Pragma("unroll") for (int r = 0; r < 4; r++) pex[sub][r] = sacc[r]; \
    } \
    __builtin_amdgcn_s_setprio(0); \
    if (kbase + 63 > qbase + wv * 16) {           /* tile touches/exceeds diag */ \
        const int q = qbase + wv * 16 + l16; \
        _Pragma("unroll") for (int sub = 0; sub < 4; sub++) \
            _Pragma("unroll") for (int r = 0; r < 4; r++) { \
                const int key = kbase + sub * 16 + quad * 4 + r; \
                if (key > q) pex[sub][r] = -1e30f; \
            } \
    } \
    _Pragma("unroll") for (int sub = 0; sub < 4; sub++) { \
        union { unsigned short s[4]; uint2 u; } pk; \
        _Pragma("unroll") for (int r = 0; r < 4; r++) pk.s[r] = f2bf(__expf(pex[sub][r])); \
        *(uint2*)&Pw[wv][l16 * 72 + sub * 16 + quad * 4] = pk.u; \
    } \
    { \
        bf16x8 pf0 = *(const bf16x8*)&Pw[wv][l16 * 72 + quad * 8]; \
        bf16x8 pf1 = *(const bf16x8*)&Pw[wv][l16 * 72 + 32 + quad * 8]; \
        __builtin_amdgcn_s_setprio(1); \
        lfr = __builtin_amdgcn_mfma_f32_16x16x32_bf16(ones, pf0, lfr, 0, 0, 0); \
        lfr = __builtin_amdgcn_mfma_f32_16x16x32_bf16(ones, pf1, lfr, 0, 0, 0); \
        _Pragma("unroll") for (int nt = 0; nt < 4; nt++) { \
            bf16x8 v0 = *(const bf16x8*)&Vt[bufi][(0 * 4 + quad) * 512 + (nt * 16 + l16) * 8]; \
            bf16x8 v1 = *(const bf16x8*)&Vt[bufi][(1 * 4 + quad) * 512 + (nt * 16 + l16) * 8]; \
            Ofr[nt] = __builtin_amdgcn_mfma_f32_16x16x32_bf16(pf0, v0, Ofr[nt], 0, 0, 0); \
            Ofr[nt] = __builtin_amdgcn_mfma_f32_16x16x32_bf16(pf1, v1, Ofr[nt], 0, 0, 0); \
        } \
        __builtin_amdgcn_s_setprio(0); \
    } \
} while (0)

    ATTN_STAGE(0, 0);
    __syncthreads();
    for (int kt = 0; kt < ntiles; ) {
        if (kt + 1 < ntiles) ATTN_STAGE(1, kt + 1);
        ATTN_COMPUTE(0, kt);
        kt++;
        if (kt >= ntiles) break;
        __syncthreads();
        if (kt + 1 < ntiles) ATTN_STAGE(0, kt + 1);
        ATTN_COMPUTE(1, kt);
        kt++;
        if (kt >= ntiles) break;
        __syncthreads();
    }

    float linv[4];
    #pragma unroll
    for (int r = 0; r < 4; r++) {
        float lq = __shfl(lfr[0], (lane & 48) | (quad * 4 + r), 64);
        linv[r] = 1.f / lq;
    }
    #pragma unroll
    for (int nt = 0; nt < 4; nt++)
        #pragma unroll
        for (int r = 0; r < 4; r++) {
            const int s = qbase + wv * 16 + quad * 4 + r;
            ao[((size_t)b * S_LEN + s) * DMODEL + h * HD + nt * 16 + l16] =
                f2bf(Ofr[nt][r] * linv[r]);
        }
#undef ATTN_STAGE
#undef ATTN_COMPUTE
}

// ---------------------------------------------------------------------------
// K3: out = ao @ w_proj_bf16^T + b_proj.  128x64 tile. Same R9 surgery:
// B (wpb) fragments direct-to-register from L2, A-only LDS dbuf (16KB),
// plain 2-phase barriers.
// ---------------------------------------------------------------------------
#define PROJ_STAGE(dA, kk) do { \
    gload_lds16(ag + (kk),               (dA) + wv * 512); \
    gload_lds16(ag + 64 * DMODEL + (kk), (dA) + 2048 + wv * 512); \
} while (0)

#define PROJ_BLOAD(BF, kk) do { \
    _Pragma("unroll") for (int n_ = 0; n_ < 2; n_++) \
        (BF)[n_] = *(const bf16x8*)(bqb + (size_t)n_ * 16 * DMODEL + (kk)); \
} while (0)

#define PROJ_COMPUTE(sA, BF) do { \
    bf16x8 af[4]; \
    _Pragma("unroll") for (int m_ = 0; m_ < 4; m_++) af[m_] = *(const bf16x8*)&(sA)[aoff[m_]]; \
    _Pragma("unroll") for (int n_ = 0; n_ < 2; n_++) { \
        _Pragma("unroll") for (int m_ = 0; m_ < 4; m_++) \
            acc[m_][n_] = __builtin_amdgcn_mfma_f32_16x16x32_bf16(af[m_], (BF)[n_], acc[m_][n_], 0, 0, 0); \
    } \
} while (0)

__global__ __launch_bounds__(256, 3) void proj_kernel(
    const unsigned short* __restrict__ a, const unsigned short* __restrict__ wpb,
    const float* __restrict__ bias, float* __restrict__ out)
{
    __shared__ __align__(16) unsigned short smem[8192];  // A dbuf only
    unsigned short* A0 = smem;
    unsigned short* A1 = smem + 4096;

    const int t = threadIdx.x;
    const int v = (blockIdx.x & 7) * 64 + (blockIdx.x >> 3);
    const int mbase = (v >> 4) * 128;
    const int nbase = (v & 15) * 64;
    const int wv = t >> 6, lane = t & 63, quad = lane >> 4, l16 = lane & 15;
    const int wr = wv >> 1, wc = wv & 1;

    floatx4 acc[4][2];
    #pragma unroll
    for (int m = 0; m < 4; m++)
        #pragma unroll
        for (int n = 0; n < 2; n++)
            #pragma unroll
            for (int r = 0; r < 4; r++) acc[m][n][r] = 0.f;

    const int srow = t >> 2;
    const int schunk = (t & 3) ^ SROW(srow);
    const unsigned short* ag = a + (size_t)(mbase + srow) * DMODEL + schunk * 8;
    const unsigned short* bqb = wpb + (size_t)(nbase + wc * 32 + l16) * DMODEL + quad * 8;

    const int Sl = SROW(l16);
    int aoff[4];
    #pragma unroll
    for (int m = 0; m < 4; m++) aoff[m] = (wr * 64 + m * 16 + l16) * 32 + (quad ^ Sl) * 8;

    bf16x8 bfc[2], bfn[2];
    PROJ_STAGE(A0, 0);
    PROJ_BLOAD(bfc, 0);
    __syncthreads();
    for (int k0 = 0; k0 < DMODEL; k0 += 64) {
        PROJ_STAGE(A1, k0 + 32);
        PROJ_BLOAD(bfn, k0 + 32);
        PROJ_COMPUTE(A0, bfc);
        __syncthreads();
        if (k0 + 64 < DMODEL) {
            PROJ_STAGE(A0, k0 + 64);
            PROJ_BLOAD(bfc, k0 + 64);
        }
        PROJ_COMPUTE(A1, bfn);
        __syncthreads();
    }

    #pragma unroll
    for (int n = 0; n < 2; n++) {
        const int nn = nbase + wc * 32 + n * 16 + l16;
        const float bvv = bias[nn];
        #pragma unroll
        for (int m = 0; m < 4; m++)
            #pragma unroll
            for (int r = 0; r < 4; r++)
                out[(size_t)(mbase + wr * 64 + m * 16 + quad * 4 + r) * DMODEL + nn] =
                    acc[m][n][r] + bvv;
    }
}

extern "C" void kernel_launch(void* const* d_in, const int* in_sizes, int n_in,
                              void* d_out, int out_size, void* d_ws, size_t ws_size,
                              hipStream_t stream) {
    const float* x      = (const float*)d_in[0];
    const float* freqs  = (const float*)d_in[2];
    const float* w_qkv  = (const float*)d_in[3];
    const float* b_qkv  = (const float*)d_in[4];
    const float* w_proj = (const float*)d_in[5];
    const float* b_proj = (const float*)d_in[6];
    float* out = (float*)d_out;

    unsigned short* ws = (unsigned short*)d_ws;
    const size_t HSZ = (size_t)2 * NH * S_LEN * HD;   // 4,194,304 shorts
    unsigned short* qb  = ws;
    unsigned short* kb  = ws + HSZ;
    unsigned short* vb  = ws + 2 * HSZ;
    unsigned short* ao  = ws + 3 * HSZ;
    unsigned short* xb  = ws + 4 * HSZ;                       // 4096x1024 bf16
    unsigned short* wqb = xb + (size_t)4096 * 1024;           // 3072x1024 bf16
    unsigned short* wpb = wqb + (size_t)3072 * 1024;          // 1024x1024 bf16
    float2* cs = (float2*)(wpb + (size_t)1024 * 1024);        // 2048x32 (cos,sin)

    prep_kernel<<<2048, 256, 0, stream>>>(x, w_qkv, w_proj, freqs, xb, wqb, wpb, cs);
    qkv_gemm_kernel<<<768, 256, 0, stream>>>(xb, wqb, b_qkv, cs, qb, kb, vb);
    attn_kernel<<<512, 512, 0, stream>>>(qb, kb, vb, ao);
    proj_kernel<<<512, 256, 0, stream>>>(ao, wpb, b_proj, out);
}

// Round 10
// 219.233 us; speedup vs baseline: 1.0492x; 1.0492x over previous
//
#include <hip/hip_runtime.h>

// Problem constants: B=2, S=2048, D=1024, H=16, HD=64
#define S_LEN 2048
#define NH 16
#define HD 64
#define DMODEL 1024

typedef __bf16 bf16x8 __attribute__((ext_vector_type(8)));
typedef float floatx4 __attribute__((ext_vector_type(4)));
typedef short short8 __attribute__((ext_vector_type(8)));

__device__ inline unsigned short f2bf(float f) {
    union { float f; unsigned u; } v; v.f = f;
    unsigned u = v.u;
    unsigned r = (u + 0x7FFFu + ((u >> 16) & 1u)) >> 16;  // RNE
    return (unsigned short)r;
}

__device__ __forceinline__ void gload_lds16(const void* g, void* l) {
    __builtin_amdgcn_global_load_lds(
        (const __attribute__((address_space(1))) unsigned int*)g,
        (__attribute__((address_space(3))) unsigned int*)l, 16, 0, 0);
}

// counted-vmcnt barrier (T4) — used by proj's ring-3.
#define WAITV_BAR(N) do { \
    asm volatile("s_waitcnt vmcnt(" #N ")\n\ts_barrier" ::: "memory"); \
    __builtin_amdgcn_sched_barrier(0); \
} while (0)

// ---------------------------------------------------------------------------
// K0: prepass. fp32 -> bf16 for x, w_qkv, w_proj (RNE), and cos/sin table.
// ---------------------------------------------------------------------------
__device__ __forceinline__ void cvt4(const float4* __restrict__ src,
                                     uint2* __restrict__ dst, int i) {
    float4 v = src[i];
    union { unsigned short u[4]; uint2 d; } o;
    o.u[0] = f2bf(v.x); o.u[1] = f2bf(v.y); o.u[2] = f2bf(v.z); o.u[3] = f2bf(v.w);
    dst[i] = o.d;
}

__global__ __launch_bounds__(256) void prep_kernel(
    const float* __restrict__ x, const float* __restrict__ wq,
    const float* __restrict__ wp, const float* __restrict__ freqs,
    unsigned short* __restrict__ xb, unsigned short* __restrict__ wqb,
    unsigned short* __restrict__ wpb, float2* __restrict__ cs)
{
    const int tid = blockIdx.x * 256 + threadIdx.x;
    const int nth = gridDim.x * 256;
    for (int i = tid; i < (4096 * 1024) / 4; i += nth) cvt4((const float4*)x, (uint2*)xb, i);
    for (int i = tid; i < (3072 * 1024) / 4; i += nth) cvt4((const float4*)wq, (uint2*)wqb, i);
    for (int i = tid; i < (1024 * 1024) / 4; i += nth) cvt4((const float4*)wp, (uint2*)wpb, i);
    for (int i = tid; i < S_LEN * 32; i += nth) {
        const float f = freqs[i];
        float2 c; c.x = cosf(f); c.y = sinf(f);
        cs[i] = c;
    }
}

// Old 2-bit swizzle (proj's 32-col tiles).
#define SROW(r) (((r) & 3) ^ (((r) >> 2) & 3))

// ---------------------------------------------------------------------------
// K1: qkv = x_bf16 @ w_qkv_bf16^T + b_qkv, fused RoPE (table) + scatter.
// NEW (R10): 256x256 tile, BK=32, 512 threads, 8 waves (2M x 4N, 128x64 per
// wave). 64KB dbuf LDS -> 1 block/CU, grid 192 (one shift, 75% CU util).
// Rationale: R7's 128^2/4-wave wall (1350cy/step) was amortization-bound
// (16 MFMA-instr/wave between barriers); here 32 MFMA-instr/wave/tile and
// the vmcnt(0) drain is issued a full tile (~2000cy) before the wait ->
// latency fully covered; plain 2-phase barriers (verified-simple schedule).
// acc = 128 VGPR/wave; at 1 block/CU (2 waves/SIMD) budget is 256 -> no
// spill (R6's trap was the 2-block/128-reg cap).
// LDS swizzle (3-bit): physical chunk (row, p) holds logical chunk
// p ^ ((row>>1)&3); staging writes and frag reads both 2-way (free).
//  q -> [bh][s][hd] row-major, PRE-SCALED by 1/sqrt(HD)=0.125 (exact)
//  k -> blocked [bh][hdblk(8)][s(2048)][8]   (RoPE applied)
//  v -> blocked [bh][sblk(256)][hd(64)][8]   (transposed via LDS tile)
// ---------------------------------------------------------------------------
#define QKV_STAGE(bi, kk) do { \
    unsigned short* A_ = smem + (bi) * 16384; \
    unsigned short* B_ = A_ + 8192; \
    gload_lds16(agp0 + (kk), A_ + wv * 512); \
    gload_lds16(agp1 + (kk), A_ + 4096 + wv * 512); \
    gload_lds16(bgp0 + (kk), B_ + wv * 512); \
    gload_lds16(bgp1 + (kk), B_ + 4096 + wv * 512); \
} while (0)

#define QKV_COMPUTE(bi) do { \
    const unsigned short* A_ = smem + (bi) * 16384; \
    const unsigned short* B_ = A_ + 8192; \
    bf16x8 af[8], bf[4]; \
    _Pragma("unroll") for (int m_ = 0; m_ < 8; m_++) af[m_] = *(const bf16x8*)&A_[aoff[m_]]; \
    _Pragma("unroll") for (int n_ = 0; n_ < 4; n_++) bf[n_] = *(const bf16x8*)&B_[boff[n_]]; \
    __builtin_amdgcn_s_setprio(1); \
    _Pragma("unroll") for (int n_ = 0; n_ < 4; n_++) \
        _Pragma("unroll") for (int m_ = 0; m_ < 8; m_++) \
            acc[m_][n_] = __builtin_amdgcn_mfma_f32_16x16x32_bf16(af[m_], bf[n_], acc[m_][n_], 0, 0, 0); \
    __builtin_amdgcn_s_setprio(0); \
} while (0)

__global__ __launch_bounds__(512, 2) void qkv_gemm_kernel(
    const unsigned short* __restrict__ xb, const unsigned short* __restrict__ wqb,
    const float* __restrict__ bias, const float2* __restrict__ cs,
    unsigned short* __restrict__ qb, unsigned short* __restrict__ kb,
    unsigned short* __restrict__ vb)
{
    // dbuf: buf i at smem + i*16384 shorts (A 16KB + B 16KB each) = 64KB.
    // V epilogue reuses smem[0..18432) as 256hd x 72 tile (36KB).
    __shared__ __align__(16) unsigned short smem[32768];

    const int t = threadIdx.x;
    const int v = (blockIdx.x & 7) * 24 + (blockIdx.x >> 3);   // XCD swizzle (192=8*24)
    const int mbase = (v / 12) * 256;   // 16 m-tiles
    const int nbase = (v % 12) * 256;   // 12 n-tiles
    const int wv = t >> 6, lane = t & 63;
    const int quad = lane >> 4, l16 = lane & 15;
    const int wr = wv >> 2, wcc = wv & 3;       // 2M x 4N wave grid

    floatx4 acc[8][4];
    #pragma unroll
    for (int m = 0; m < 8; m++)
        #pragma unroll
        for (int n = 0; n < 4; n++)
            #pragma unroll
            for (int r = 0; r < 4; r++) acc[m][n][r] = 0.f;

    // Staging: thread t owns physical chunks {t, t+512} of each 1024-chunk
    // (16KB) tile half-pair. chunk c: row=c>>2, pcol=c&3; source supplies
    // logical chunk pcol ^ ((row>>1)&3). (row+128 has same swizzle bits.)
    const int r0 = t >> 2;
    const int sc0 = (t & 3) ^ ((r0 >> 1) & 3);
    const unsigned short* agp0 = xb + (size_t)(mbase + r0) * DMODEL + sc0 * 8;
    const unsigned short* agp1 = xb + (size_t)(mbase + r0 + 128) * DMODEL + sc0 * 8;
    const unsigned short* bgp0 = wqb + (size_t)(nbase + r0) * DMODEL + sc0 * 8;
    const unsigned short* bgp1 = wqb + (size_t)(nbase + r0 + 128) * DMODEL + sc0 * 8;

    // Fragment read offsets (shorts): row*32 + (quad ^ ((row>>1)&3))*8.
    int aoff[8], boff[4];
    #pragma unroll
    for (int m = 0; m < 8; m++) {
        const int row = wr * 128 + m * 16 + l16;
        aoff[m] = row * 32 + ((quad ^ ((row >> 1) & 3)) * 8);
    }
    #pragma unroll
    for (int n = 0; n < 4; n++) {
        const int row = wcc * 64 + n * 16 + l16;
        boff[n] = row * 32 + ((quad ^ ((row >> 1) & 3)) * 8);
    }

    QKV_STAGE(0, 0);
    __syncthreads();                       // prologue drain
    for (int kt = 0; kt < 32; kt++) {
        if (kt + 1 < 32) QKV_STAGE((kt + 1) & 1, (kt + 1) * 32);
        QKV_COMPUTE(kt & 1);               // stage issued a full tile before its wait
        __syncthreads();                   // drain: loads landed ~2000cy ago -> cheap
    }

    // nbase multiple of 256; 1024%256==0 -> no q/k/v part crossing; 4 heads.
    const int part = nbase >> 10;                 // 0=q 1=k 2=v
    const int bidx = mbase >> 11;                 // 4096/256=16 rows tiles; batch at 2048 ok
    const int s0   = mbase & 2047;
    const int hb   = (nbase & 1023) >> 6;         // base head (4 heads/block)

    if (part == 2) {
        // ---- V: bias, transpose 256(s) x 256(hd) in 4 s-chunks of 64 via LDS
        unsigned short* Vt = smem;                // 256 hd x 72 = 18432 shorts
        float bvv[4];
        #pragma unroll
        for (int nt = 0; nt < 4; nt++) bvv[nt] = bias[nbase + wcc * 64 + nt * 16 + l16];
        #pragma unroll
        for (int ch = 0; ch < 4; ch++) {
            __syncthreads();
            if (wr == (ch >> 1)) {                // 4 waves (wcc 0..3) cover 256 hd
                const int mb = (ch & 1) * 4;
                #pragma unroll
                for (int nt = 0; nt < 4; nt++) {
                    const int hdl = wcc * 64 + nt * 16 + l16;
                    #pragma unroll
                    for (int mm = 0; mm < 4; mm++)
                        #pragma unroll
                        for (int r = 0; r < 4; r++)
                            Vt[hdl * 72 + mm * 16 + quad * 4 + r] =
                                f2bf(acc[mb + mm][nt][r] + bvv[nt]);
                }
            }
            __syncthreads();
            const int hd = t & 255, sp = t >> 8;  // sp: 0..1
            const size_t bh2 = (size_t)bidx * NH + hb + (hd >> 6);
            #pragma unroll
            for (int c = 0; c < 4; c++) {
                const int sl0 = (sp * 4 + c) * 8;
                const int sg = s0 + ch * 64 + sl0;
                short8 vv = *(const short8*)&Vt[hd * 72 + sl0];
                *(short8*)&vb[((bh2 * 256 + (sg >> 3)) * 64 + (hd & 63)) * 8] = vv;
            }
        }
    } else {
        // ---- Q/K: bias + RoPE from table. Pair = adjacent col = adjacent l16.
        const size_t bhb = (size_t)bidx * NH;
        const int odd = l16 & 1;
        #pragma unroll
        for (int nt = 0; nt < 4; nt++) {
            const int n_ = nbase + wcc * 64 + nt * 16 + l16;
            const int hd = n_ & 63;               // = nt*16 + l16
            const size_t bh = bhb + ((n_ & 1023) >> 6);
            const float bvv = bias[n_];
            const int ci = hd >> 1;
            #pragma unroll
            for (int m = 0; m < 8; m++) {
                #pragma unroll
                for (int r = 0; r < 4; r++) {
                    const int s = s0 + wr * 128 + m * 16 + quad * 4 + r;
                    float val = acc[m][nt][r] + bvv;
                    float other = __shfl_xor(val, 1, 64);
                    const float2 csv = cs[(size_t)s * 32 + ci];
                    float outv = odd ? fmaf(other, csv.y, val * csv.x)
                                     : fmaf(-other, csv.y, val * csv.x);
                    if (part == 0) {
                        qb[(bh * S_LEN + s) * HD + hd] = f2bf(outv * 0.125f);
                    } else {
                        kb[((bh * 8 + (hd >> 3)) * (size_t)S_LEN + s) * 8 + (hd & 7)] = f2bf(outv);
                    }
                }
            }
        }
    }
}

// ---------------------------------------------------------------------------
// K2: causal flash attention (R7 verbatim: QBLK=64, 2-phase dbuf staging,
// reversed qt launch, setprio).
// ---------------------------------------------------------------------------
__global__ __launch_bounds__(256, 3) void attn_kernel(
    const unsigned short* __restrict__ qb, const unsigned short* __restrict__ kb,
    const unsigned short* __restrict__ vbk, unsigned short* __restrict__ ao)
{
    __shared__ __align__(16) unsigned short Ks[2][8 * 512];
    __shared__ __align__(16) unsigned short Vt[2][8 * 512];
    __shared__ __align__(16) unsigned short Pw[4][16 * 72];

    const int t = threadIdx.x;
    const int wv = t >> 6, lane = t & 63, quad = lane >> 4, l16 = lane & 15;
    const int qt   = 31 - (blockIdx.x >> 5);      // reversed: long blocks first
    const int bhid = blockIdx.x & 31;
    const int h = bhid & 15, b = bhid >> 4;
    const size_t bh = (size_t)b * NH + h;
    const unsigned short* qg  = qb + bh * S_LEN * HD;
    const unsigned short* kgB = kb + bh * 8 * S_LEN * 8;
    const unsigned short* vgB = vbk + bh * 256 * 64 * 8;

    bf16x8 qf[2];
    {
        const unsigned short* q0 = qg + (size_t)(qt * 64 + wv * 16 + l16) * HD;
        qf[0] = *(const bf16x8*)&q0[quad * 8];
        qf[1] = *(const bf16x8*)&q0[32 + quad * 8];
    }

    bf16x8 ones;
    {
        union { short8 s; bf16x8 v; } o;
        for (int j = 0; j < 8; j++) o.s[j] = 0x3F80;
        ones = o.v;
    }

    floatx4 lfr = {0.f, 0.f, 0.f, 0.f};
    floatx4 Ofr[4];
    for (int nt = 0; nt < 4; nt++)
        for (int r = 0; r < 4; r++) Ofr[nt][r] = 0.f;

    const int ntiles = qt + 1;

#define ATTN_STAGE(bufi, kt_) do { \
    const int kb_ = (kt_) * 64; \
    const unsigned short* g0 = kgB + ((size_t)(2 * wv) * S_LEN + kb_ + lane) * 8; \
    gload_lds16(g0,             &Ks[bufi][(2 * wv) * 512]); \
    gload_lds16(g0 + S_LEN * 8, &Ks[bufi][(2 * wv + 1) * 512]); \
    const unsigned short* g1 = vgB + ((size_t)((kb_ >> 3) + 2 * wv) * 64 + lane) * 8; \
    gload_lds16(g1,          &Vt[bufi][(2 * wv) * 512]); \
    gload_lds16(g1 + 64 * 8, &Vt[bufi][(2 * wv + 1) * 512]); \
} while (0)

#define ATTN_COMPUTE(bufi, kt_) do { \
    const int kbase = (kt_) * 64; \
    float pex[4][4]; \
    __builtin_amdgcn_s_setprio(1); \
    _Pragma("unroll") for (int sub = 0; sub < 4; sub++) { \
        bf16x8 kf0 = *(const bf16x8*)&Ks[bufi][(0 * 4 + quad) * 512 + (sub * 16 + l16) * 8]; \
        bf16x8 kf1 = *(const bf16x8*)&Ks[bufi][(1 * 4 + quad) * 512 + (sub * 16 + l16) * 8]; \
        floatx4 sacc = {0.f, 0.f, 0.f, 0.f}; \
        sacc = __builtin_amdgcn_mfma_f32_16x16x32_bf16(kf0, qf[0], sacc, 0, 0, 0); \
        sacc = __builtin_amdgcn_mfma_f32_16x16x32_bf16(kf1, qf[1], sacc, 0, 0, 0); \
        _Pragma("unroll") for (int r = 0; r < 4; r++) pex[sub][r] = sacc[r]; \
    } \
    __builtin_amdgcn_s_setprio(0); \
    if ((kt_) == qt) { \
        const int q = qt * 64 + wv * 16 + l16; \
        _Pragma("unroll") for (int sub = 0; sub < 4; sub++) \
            _Pragma("unroll") for (int r = 0; r < 4; r++) { \
                const int key = kbase + sub * 16 + quad * 4 + r; \
                if (key > q) pex[sub][r] = -1e30f; \
            } \
    } \
    _Pragma("unroll") for (int sub = 0; sub < 4; sub++) { \
        union { unsigned short s[4]; uint2 u; } pk; \
        _Pragma("unroll") for (int r = 0; r < 4; r++) pk.s[r] = f2bf(__expf(pex[sub][r])); \
        *(uint2*)&Pw[wv][l16 * 72 + sub * 16 + quad * 4] = pk.u; \
    } \
    { \
        bf16x8 pf0 = *(const bf16x8*)&Pw[wv][l16 * 72 + quad * 8]; \
        bf16x8 pf1 = *(const bf16x8*)&Pw[wv][l16 * 72 + 32 + quad * 8]; \
        __builtin_amdgcn_s_setprio(1); \
        lfr = __builtin_amdgcn_mfma_f32_16x16x32_bf16(ones, pf0, lfr, 0, 0, 0); \
        lfr = __builtin_amdgcn_mfma_f32_16x16x32_bf16(ones, pf1, lfr, 0, 0, 0); \
        _Pragma("unroll") for (int nt = 0; nt < 4; nt++) { \
            bf16x8 v0 = *(const bf16x8*)&Vt[bufi][(0 * 4 + quad) * 512 + (nt * 16 + l16) * 8]; \
            bf16x8 v1 = *(const bf16x8*)&Vt[bufi][(1 * 4 + quad) * 512 + (nt * 16 + l16) * 8]; \
            Ofr[nt] = __builtin_amdgcn_mfma_f32_16x16x32_bf16(pf0, v0, Ofr[nt], 0, 0, 0); \
            Ofr[nt] = __builtin_amdgcn_mfma_f32_16x16x32_bf16(pf1, v1, Ofr[nt], 0, 0, 0); \
        } \
        __builtin_amdgcn_s_setprio(0); \
    } \
} while (0)

    ATTN_STAGE(0, 0);
    __syncthreads();
    for (int kt = 0; kt < ntiles; ) {
        if (kt + 1 < ntiles) ATTN_STAGE(1, kt + 1);
        ATTN_COMPUTE(0, kt);
        kt++;
        if (kt >= ntiles) break;
        __syncthreads();
        if (kt + 1 < ntiles) ATTN_STAGE(0, kt + 1);
        ATTN_COMPUTE(1, kt);
        kt++;
        if (kt >= ntiles) break;
        __syncthreads();
    }

    float linv[4];
    #pragma unroll
    for (int r = 0; r < 4; r++) {
        float lq = __shfl(lfr[0], (lane & 48) | (quad * 4 + r), 64);
        linv[r] = 1.f / lq;
    }
    #pragma unroll
    for (int nt = 0; nt < 4; nt++)
        #pragma unroll
        for (int r = 0; r < 4; r++) {
            const int s = qt * 64 + wv * 16 + quad * 4 + r;
            ao[((size_t)b * S_LEN + s) * DMODEL + h * HD + nt * 16 + l16] =
                f2bf(Ofr[nt][r] * linv[r]);
        }
#undef ATTN_STAGE
#undef ATTN_COMPUTE
}

// ---------------------------------------------------------------------------
// K3: out = ao @ w_proj_bf16^T + b_proj.  128x64 tile, ring-3 counted-vmcnt
// (R7 verbatim).
// ---------------------------------------------------------------------------
#define PROJ_STAGE(bi, kk) do { \
    unsigned short* dA_ = smem + (bi) * 6144; \
    unsigned short* dB_ = dA_ + 4096; \
    gload_lds16(ag + (kk),               dA_ + wv * 512); \
    gload_lds16(ag + 64 * DMODEL + (kk), dA_ + 2048 + wv * 512); \
    gload_lds16(bg + (kk),               dB_ + wv * 512); \
} while (0)

#define PROJ_COMPUTE(bi) do { \
    const unsigned short* sA_ = smem + (bi) * 6144; \
    const unsigned short* sB_ = sA_ + 4096; \
    bf16x8 af[4]; \
    _Pragma("unroll") for (int m_ = 0; m_ < 4; m_++) af[m_] = *(const bf16x8*)&sA_[aoff[m_]]; \
    _Pragma("unroll") for (int n_ = 0; n_ < 2; n_++) { \
        bf16x8 bf = *(const bf16x8*)&sB_[boff[n_]]; \
        _Pragma("unroll") for (int m_ = 0; m_ < 4; m_++) \
            acc[m_][n_] = __builtin_amdgcn_mfma_f32_16x16x32_bf16(af[m_], bf, acc[m_][n_], 0, 0, 0); \
    } \
} while (0)

__global__ __launch_bounds__(256, 3) void proj_kernel(
    const unsigned short* __restrict__ a, const unsigned short* __restrict__ wpb,
    const float* __restrict__ bias, float* __restrict__ out)
{
    __shared__ __align__(16) unsigned short smem[18432];

    const int t = threadIdx.x;
    const int v = (blockIdx.x & 7) * 64 + (blockIdx.x >> 3);
    const int mbase = (v >> 4) * 128;
    const int nbase = (v & 15) * 64;
    const int wv = t >> 6, lane = t & 63, quad = lane >> 4, l16 = lane & 15;
    const int wr = wv >> 1, wc = wv & 1;

    floatx4 acc[4][2];
    #pragma unroll
    for (int m = 0; m < 4; m++)
        #pragma unroll
        for (int n = 0; n < 2; n++)
            #pragma unroll
            for (int r = 0; r < 4; r++) acc[m][n][r] = 0.f;

    const int srow = t >> 2;
    const int schunk = (t & 3) ^ SROW(srow);
    const unsigned short* ag = a + (size_t)(mbase + srow) * DMODEL + schunk * 8;
    const unsigned short* bg = wpb + (size_t)(nbase + srow) * DMODEL + schunk * 8;

    const int Sl = SROW(l16);
    int aoff[4], boff[2];
    #pragma unroll
    for (int m = 0; m < 4; m++) aoff[m] = (wr * 64 + m * 16 + l16) * 32 + (quad ^ Sl) * 8;
    #pragma unroll
    for (int n = 0; n < 2; n++) boff[n] = (wc * 32 + n * 16 + l16) * 32 + (quad ^ Sl) * 8;

    PROJ_STAGE(0, 0);
    PROJ_STAGE(1, 32);
    for (int tb = 0; tb < 30; tb += 3) {
        WAITV_BAR(3); PROJ_STAGE(2, (tb + 2) * 32); PROJ_COMPUTE(0);
        WAITV_BAR(3); PROJ_STAGE(0, (tb + 3) * 32); PROJ_COMPUTE(1);
        WAITV_BAR(3); PROJ_STAGE(1, (tb + 4) * 32); PROJ_COMPUTE(2);
    }
    WAITV_BAR(3); PROJ_COMPUTE(0);   // tile 30
    WAITV_BAR(0); PROJ_COMPUTE(1);   // tile 31

    #pragma unroll
    for (int n = 0; n < 2; n++) {
        const int nn = nbase + wc * 32 + n * 16 + l16;
        const float bvv = bias[nn];
        #pragma unroll
        for (int m = 0; m < 4; m++)
            #pragma unroll
            for (int r = 0; r < 4; r++)
                out[(size_t)(mbase + wr * 64 + m * 16 + quad * 4 + r) * DMODEL + nn] =
                    acc[m][n][r] + bvv;
    }
}

extern "C" void kernel_launch(void* const* d_in, const int* in_sizes, int n_in,
                              void* d_out, int out_size, void* d_ws, size_t ws_size,
                              hipStream_t stream) {
    const float* x      = (const float*)d_in[0];
    const float* freqs  = (const float*)d_in[2];
    const float* w_qkv  = (const float*)d_in[3];
    const float* b_qkv  = (const float*)d_in[4];
    const float* w_proj = (const float*)d_in[5];
    const float* b_proj = (const float*)d_in[6];
    float* out = (float*)d_out;

    unsigned short* ws = (unsigned short*)d_ws;
    const size_t HSZ = (size_t)2 * NH * S_LEN * HD;   // 4,194,304 shorts
    unsigned short* qb  = ws;
    unsigned short* kb  = ws + HSZ;
    unsigned short* vb  = ws + 2 * HSZ;
    unsigned short* ao  = ws + 3 * HSZ;
    unsigned short* xb  = ws + 4 * HSZ;                       // 4096x1024 bf16
    unsigned short* wqb = xb + (size_t)4096 * 1024;           // 3072x1024 bf16
    unsigned short* wpb = wqb + (size_t)3072 * 1024;          // 1024x1024 bf16
    float2* cs = (float2*)(wpb + (size_t)1024 * 1024);        // 2048x32 (cos,sin)

    prep_kernel<<<2048, 256, 0, stream>>>(x, w_qkv, w_proj, freqs, xb, wqb, wpb, cs);
    qkv_gemm_kernel<<<192, 512, 0, stream>>>(xb, wqb, b_qkv, cs, qb, kb, vb);
    attn_kernel<<<1024, 256, 0, stream>>>(qb, kb, vb, ao);
    proj_kernel<<<512, 256, 0, stream>>>(ao, wpb, b_proj, out);
}

// Round 11
// 202.937 us; speedup vs baseline: 1.1334x; 1.0803x over previous
//
#include <hip/hip_runtime.h>

// Problem constants: B=2, S=2048, D=1024, H=16, HD=64
#define S_LEN 2048
#define NH 16
#define HD 64
#define DMODEL 1024

typedef __bf16 bf16x8 __attribute__((ext_vector_type(8)));
typedef float floatx4 __attribute__((ext_vector_type(4)));
typedef short short8 __attribute__((ext_vector_type(8)));

__device__ inline unsigned short f2bf(float f) {
    union { float f; unsigned u; } v; v.f = f;
    unsigned u = v.u;
    unsigned r = (u + 0x7FFFu + ((u >> 16) & 1u)) >> 16;  // RNE
    return (unsigned short)r;
}

__device__ __forceinline__ void gload_lds16(const void* g, void* l) {
    __builtin_amdgcn_global_load_lds(
        (const __attribute__((address_space(1))) unsigned int*)g,
        (__attribute__((address_space(3))) unsigned int*)l, 16, 0, 0);
}

// counted-vmcnt barrier (T4): wait own oldest loads BEFORE the barrier; newer
// loads (up to N) stay in flight ACROSS it.
#define WAITV_BAR(N) do { \
    asm volatile("s_waitcnt vmcnt(" #N ")\n\ts_barrier" ::: "memory"); \
    __builtin_amdgcn_sched_barrier(0); \
} while (0)

// ---------------------------------------------------------------------------
// K0: prepass. fp32 -> bf16 for x, w_qkv, w_proj (RNE), and cos/sin table.
// ---------------------------------------------------------------------------
__device__ __forceinline__ void cvt4(const float4* __restrict__ src,
                                     uint2* __restrict__ dst, int i) {
    float4 v = src[i];
    union { unsigned short u[4]; uint2 d; } o;
    o.u[0] = f2bf(v.x); o.u[1] = f2bf(v.y); o.u[2] = f2bf(v.z); o.u[3] = f2bf(v.w);
    dst[i] = o.d;
}

__global__ __launch_bounds__(256) void prep_kernel(
    const float* __restrict__ x, const float* __restrict__ wq,
    const float* __restrict__ wp, const float* __restrict__ freqs,
    unsigned short* __restrict__ xb, unsigned short* __restrict__ wqb,
    unsigned short* __restrict__ wpb, float2* __restrict__ cs)
{
    const int tid = blockIdx.x * 256 + threadIdx.x;
    const int nth = gridDim.x * 256;
    for (int i = tid; i < (4096 * 1024) / 4; i += nth) cvt4((const float4*)x, (uint2*)xb, i);
    for (int i = tid; i < (3072 * 1024) / 4; i += nth) cvt4((const float4*)wq, (uint2*)wqb, i);
    for (int i = tid; i < (1024 * 1024) / 4; i += nth) cvt4((const float4*)wp, (uint2*)wpb, i);
    for (int i = tid; i < S_LEN * 32; i += nth) {
        const float f = freqs[i];
        float2 c; c.x = cosf(f); c.y = sinf(f);
        cs[i] = c;
    }
}

// Bank swizzle for 32-col (4x16B-chunk) row-major LDS tiles.
#define SROW(r) (((r) & 3) ^ (((r) >> 2) & 3))

// ---------------------------------------------------------------------------
// K1: qkv = x_bf16 @ w_qkv_bf16^T + b_qkv, fused RoPE (table) + scatter.
// R7-proven (best-measured 54us): 128x128 tile, 4 waves, BK=32, ring-3
// counted-vmcnt, 48KB LDS, 3 blocks/CU, grid 768 co-resident.
// [R10's 256^2 attempt spilled: acc=128 starves the unified file ->
//  WRITE_SIZE +30MB; geometry (N=3072 -> 192 tiles) caps 256^2 at 0.75 util.]
// ---------------------------------------------------------------------------
#define QKV_STAGE(bi, kk) do { \
    unsigned short* dA_ = smem + (bi) * 8192; \
    unsigned short* dB_ = dA_ + 4096; \
    gload_lds16(ag + (kk),               dA_ + wv * 512); \
    gload_lds16(ag + 64 * DMODEL + (kk), dA_ + 2048 + wv * 512); \
    gload_lds16(bg + (kk),               dB_ + wv * 512); \
    gload_lds16(bg + 64 * DMODEL + (kk), dB_ + 2048 + wv * 512); \
} while (0)

#define QKV_COMPUTE(bi) do { \
    const unsigned short* sA_ = smem + (bi) * 8192; \
    const unsigned short* sB_ = sA_ + 4096; \
    bf16x8 af[4]; \
    _Pragma("unroll") for (int m_ = 0; m_ < 4; m_++) af[m_] = *(const bf16x8*)&sA_[aoff[m_]]; \
    _Pragma("unroll") for (int n_ = 0; n_ < 4; n_++) { \
        bf16x8 bf = *(const bf16x8*)&sB_[boff[n_]]; \
        _Pragma("unroll") for (int m_ = 0; m_ < 4; m_++) \
            acc[m_][n_] = __builtin_amdgcn_mfma_f32_16x16x32_bf16(af[m_], bf, acc[m_][n_], 0, 0, 0); \
    } \
} while (0)

__global__ __launch_bounds__(256, 3) void qkv_gemm_kernel(
    const unsigned short* __restrict__ xb, const unsigned short* __restrict__ wqb,
    const float* __restrict__ bias, const float2* __restrict__ cs,
    unsigned short* __restrict__ qb, unsigned short* __restrict__ kb,
    unsigned short* __restrict__ vb)
{
    // ring-3: slot i at smem + i*8192 (A 4096 shorts, B 4096 shorts) = 48KB.
    // V epilogue reuses smem as 128x72 tile (9216 shorts).
    __shared__ __align__(16) unsigned short smem[24576];

    const int t = threadIdx.x;
    const int v = (blockIdx.x & 7) * 96 + (blockIdx.x >> 3);   // XCD swizzle
    const int mbase = (v / 24) * 128;   // 32 m-tiles
    const int nbase = (v % 24) * 128;   // 24 n-tiles
    const int wv = t >> 6, lane = t & 63;
    const int quad = lane >> 4, l16 = lane & 15;
    const int wr = wv >> 1, wc = wv & 1;

    floatx4 acc[4][4];
    #pragma unroll
    for (int m = 0; m < 4; m++)
        #pragma unroll
        for (int n = 0; n < 4; n++)
            #pragma unroll
            for (int r = 0; r < 4; r++) acc[m][n][r] = 0.f;

    const int srow = t >> 2;
    const int schunk = (t & 3) ^ SROW(srow);
    const unsigned short* ag = xb + (size_t)(mbase + srow) * DMODEL + schunk * 8;
    const unsigned short* bg = wqb + (size_t)(nbase + srow) * DMODEL + schunk * 8;

    const int Sl = SROW(l16);
    int aoff[4], boff[4];
    #pragma unroll
    for (int m = 0; m < 4; m++) aoff[m] = (wr * 64 + m * 16 + l16) * 32 + (quad ^ Sl) * 8;
    #pragma unroll
    for (int n = 0; n < 4; n++) boff[n] = (wc * 64 + n * 16 + l16) * 32 + (quad ^ Sl) * 8;

    // Ring-3 schedule. At iter t's WAITV_BAR: tiles {t,t+1} in flight (8
    // loads); vmcnt(4) -> tile t landed for this wave; barrier -> for all
    // waves, and all waves finished COMPUTE(t-1) (slot (t+2)%3) -> restage.
    QKV_STAGE(0, 0);
    QKV_STAGE(1, 32);
    for (int tb = 0; tb < 30; tb += 3) {
        WAITV_BAR(4); QKV_STAGE(2, (tb + 2) * 32); QKV_COMPUTE(0);
        WAITV_BAR(4); QKV_STAGE(0, (tb + 3) * 32); QKV_COMPUTE(1);
        WAITV_BAR(4); QKV_STAGE(1, (tb + 4) * 32); QKV_COMPUTE(2);
    }
    WAITV_BAR(4); QKV_COMPUTE(0);    // tile 30
    WAITV_BAR(0); QKV_COMPUTE(1);    // tile 31

    const int part = nbase >> 10;                 // 0=q 1=k 2=v
    const int bidx = mbase >> 11;
    const int s0   = mbase & 2047;

    if (part == 2) {
        unsigned short* Vt = smem;                // 128 hd x 72 s-pad
        const int hb = (nbase & 1023) >> 6;
        float bvv[4];
        #pragma unroll
        for (int nt = 0; nt < 4; nt++) bvv[nt] = bias[nbase + wc * 64 + nt * 16 + l16];
        #pragma unroll
        for (int shalf = 0; shalf < 2; shalf++) {
            __syncthreads();
            if (wr == shalf) {
                #pragma unroll
                for (int nt = 0; nt < 4; nt++) {
                    const int hdl = wc * 64 + nt * 16 + l16;
                    #pragma unroll
                    for (int m = 0; m < 4; m++)
                        #pragma unroll
                        for (int r = 0; r < 4; r++)
                            Vt[hdl * 72 + m * 16 + quad * 4 + r] = f2bf(acc[m][nt][r] + bvv[nt]);
                }
            }
            __syncthreads();
            const int hdl = t & 127, sp = t >> 7;
            const size_t bh2 = (size_t)bidx * NH + hb + (hdl >> 6);
            #pragma unroll
            for (int c = 0; c < 4; c++) {
                const int sl0 = (sp * 4 + c) * 8;
                const int sg = s0 + shalf * 64 + sl0;
                short8 vv = *(const short8*)&Vt[hdl * 72 + sl0];
                *(short8*)&vb[((bh2 * 256 + (sg >> 3)) * 64 + (hdl & 63)) * 8] = vv;
            }
        }
    } else {
        const size_t bhb = (size_t)bidx * NH;
        const int odd = l16 & 1;
        #pragma unroll
        for (int nt = 0; nt < 4; nt++) {
            const int n_ = nbase + wc * 64 + nt * 16 + l16;
            const int hd = n_ & 63;
            const size_t bh = bhb + ((n_ & 1023) >> 6);
            const float bvv = bias[n_];
            const int ci = (nt * 16 + l16) >> 1;
            #pragma unroll
            for (int m = 0; m < 4; m++) {
                #pragma unroll
                for (int r = 0; r < 4; r++) {
                    const int s = s0 + wr * 64 + m * 16 + quad * 4 + r;
                    float val = acc[m][nt][r] + bvv;
                    float other = __shfl_xor(val, 1, 64);
                    const float2 csv = cs[(size_t)s * 32 + ci];
                    float outv = odd ? fmaf(other, csv.y, val * csv.x)
                                     : fmaf(-other, csv.y, val * csv.x);
                    if (part == 0) {
                        qb[(bh * S_LEN + s) * HD + hd] = f2bf(outv * 0.125f);
                    } else {
                        kb[((bh * 8 + (hd >> 3)) * (size_t)S_LEN + s) * 8 + (hd & 7)] = f2bf(outv);
                    }
                }
            }
        }
    }
}

// ---------------------------------------------------------------------------
// K2: causal flash attention. NEW (R11): 32 q-rows PER WAVE (cg=0/1 pairs),
// QBLK=128, 4 waves, 256 threads, grid 512 (16 qp x 32 bh, reversed).
// Mechanism: K/V fragments are read from LDS once and feed 2x the MFMA
// (24 MFMA per ~21KB ds_read vs 12 per 18KB) -> LDS traffic, barriers and
// staging traffic PER OUTPUT ROW all halve. (R8's QBLK=128 via more waves
// was neutral because bytes-per-output is set by q-rows per WAVE.)
// LDS 50KB -> 3 blocks/CU (12 waves/CU, 170-reg cap, ~150 used).
// ---------------------------------------------------------------------------
__global__ __launch_bounds__(256, 3) void attn_kernel(
    const unsigned short* __restrict__ qb, const unsigned short* __restrict__ kb,
    const unsigned short* __restrict__ vbk, unsigned short* __restrict__ ao)
{
    __shared__ __align__(16) unsigned short Ks[2][8 * 512];
    __shared__ __align__(16) unsigned short Vt[2][8 * 512];
    __shared__ __align__(16) unsigned short Pw[4][32 * 72];

    const int t = threadIdx.x;
    const int wv = t >> 6, lane = t & 63, quad = lane >> 4, l16 = lane & 15;
    const int qp = 15 - (blockIdx.x >> 5);        // reversed: long blocks first
    const int qbase = qp * 128;
    const int bhid = blockIdx.x & 31;
    const int h = bhid & 15, b = bhid >> 4;
    const size_t bh = (size_t)b * NH + h;
    const unsigned short* qg  = qb + bh * S_LEN * HD;
    const unsigned short* kgB = kb + bh * 8 * S_LEN * 8;
    const unsigned short* vgB = vbk + bh * 256 * 64 * 8;

    // wave wv owns q rows qbase + wv*32 + cg*16 + l16, cg in {0,1}
    bf16x8 qf[2][2];
    #pragma unroll
    for (int cg = 0; cg < 2; cg++) {
        const unsigned short* q0 = qg + (size_t)(qbase + wv * 32 + cg * 16 + l16) * HD;
        qf[cg][0] = *(const bf16x8*)&q0[quad * 8];
        qf[cg][1] = *(const bf16x8*)&q0[32 + quad * 8];
    }

    bf16x8 ones;
    {
        union { short8 s; bf16x8 v; } o;
        for (int j = 0; j < 8; j++) o.s[j] = 0x3F80;
        ones = o.v;
    }

    floatx4 lfr[2];
    floatx4 Ofr[2][4];
    #pragma unroll
    for (int cg = 0; cg < 2; cg++) {
        for (int r = 0; r < 4; r++) lfr[cg][r] = 0.f;
        for (int nt = 0; nt < 4; nt++)
            for (int r = 0; r < 4; r++) Ofr[cg][nt][r] = 0.f;
    }

    const int ntiles = (qbase >> 6) + 2;          // covers q rows qbase..qbase+127

#define ATTN_STAGE(bufi, kt_) do { \
    const int kb_ = (kt_) * 64; \
    const unsigned short* g0 = kgB + ((size_t)(2 * wv) * S_LEN + kb_ + lane) * 8; \
    gload_lds16(g0,             &Ks[bufi][(2 * wv) * 512]); \
    gload_lds16(g0 + S_LEN * 8, &Ks[bufi][(2 * wv + 1) * 512]); \
    const unsigned short* g1 = vgB + ((size_t)((kb_ >> 3) + 2 * wv) * 64 + lane) * 8; \
    gload_lds16(g1,          &Vt[bufi][(2 * wv) * 512]); \
    gload_lds16(g1 + 64 * 8, &Vt[bufi][(2 * wv + 1) * 512]); \
} while (0)

#define ATTN_COMPUTE(bufi, kt_) do { \
    const int kbase = (kt_) * 64; \
    float pex[2][4][4]; \
    __builtin_amdgcn_s_setprio(1); \
    _Pragma("unroll") for (int sub = 0; sub < 4; sub++) { \
        bf16x8 kf0 = *(const bf16x8*)&Ks[bufi][(0 * 4 + quad) * 512 + (sub * 16 + l16) * 8]; \
        bf16x8 kf1 = *(const bf16x8*)&Ks[bufi][(1 * 4 + quad) * 512 + (sub * 16 + l16) * 8]; \
        _Pragma("unroll") for (int cg = 0; cg < 2; cg++) { \
            floatx4 sacc = {0.f, 0.f, 0.f, 0.f}; \
            sacc = __builtin_amdgcn_mfma_f32_16x16x32_bf16(kf0, qf[cg][0], sacc, 0, 0, 0); \
            sacc = __builtin_amdgcn_mfma_f32_16x16x32_bf16(kf1, qf[cg][1], sacc, 0, 0, 0); \
            _Pragma("unroll") for (int r = 0; r < 4; r++) pex[cg][sub][r] = sacc[r]; \
        } \
    } \
    __builtin_amdgcn_s_setprio(0); \
    _Pragma("unroll") for (int cg = 0; cg < 2; cg++) { \
        if (kbase + 63 > qbase + wv * 32 + cg * 16) {   /* tile touches diag */ \
            const int q = qbase + wv * 32 + cg * 16 + l16; \
            _Pragma("unroll") for (int sub = 0; sub < 4; sub++) \
                _Pragma("unroll") for (int r = 0; r < 4; r++) { \
                    const int key = kbase + sub * 16 + quad * 4 + r; \
                    if (key > q) pex[cg][sub][r] = -1e30f; \
                } \
        } \
        _Pragma("unroll") for (int sub = 0; sub < 4; sub++) { \
            union { unsigned short s[4]; uint2 u; } pk; \
            _Pragma("unroll") for (int r = 0; r < 4; r++) pk.s[r] = f2bf(__expf(pex[cg][sub][r])); \
            *(uint2*)&Pw[wv][(cg * 16 + l16) * 72 + sub * 16 + quad * 4] = pk.u; \
        } \
    } \
    { \
        bf16x8 pf[2][2]; \
        _Pragma("unroll") for (int cg = 0; cg < 2; cg++) { \
            pf[cg][0] = *(const bf16x8*)&Pw[wv][(cg * 16 + l16) * 72 + quad * 8]; \
            pf[cg][1] = *(const bf16x8*)&Pw[wv][(cg * 16 + l16) * 72 + 32 + quad * 8]; \
            lfr[cg] = __builtin_amdgcn_mfma_f32_16x16x32_bf16(ones, pf[cg][0], lfr[cg], 0, 0, 0); \
            lfr[cg] = __builtin_amdgcn_mfma_f32_16x16x32_bf16(ones, pf[cg][1], lfr[cg], 0, 0, 0); \
        } \
        __builtin_amdgcn_s_setprio(1); \
        _Pragma("unroll") for (int nt = 0; nt < 4; nt++) { \
            bf16x8 v0 = *(const bf16x8*)&Vt[bufi][(0 * 4 + quad) * 512 + (nt * 16 + l16) * 8]; \
            bf16x8 v1 = *(const bf16x8*)&Vt[bufi][(1 * 4 + quad) * 512 + (nt * 16 + l16) * 8]; \
            _Pragma("unroll") for (int cg = 0; cg < 2; cg++) { \
                Ofr[cg][nt] = __builtin_amdgcn_mfma_f32_16x16x32_bf16(pf[cg][0], v0, Ofr[cg][nt], 0, 0, 0); \
                Ofr[cg][nt] = __builtin_amdgcn_mfma_f32_16x16x32_bf16(pf[cg][1], v1, Ofr[cg][nt], 0, 0, 0); \
            } \
        } \
        __builtin_amdgcn_s_setprio(0); \
    } \
} while (0)

    ATTN_STAGE(0, 0);
    __syncthreads();
    for (int kt = 0; kt < ntiles; ) {
        if (kt + 1 < ntiles) ATTN_STAGE(1, kt + 1);
        ATTN_COMPUTE(0, kt);
        kt++;
        if (kt >= ntiles) break;
        __syncthreads();
        if (kt + 1 < ntiles) ATTN_STAGE(0, kt + 1);
        ATTN_COMPUTE(1, kt);
        kt++;
        if (kt >= ntiles) break;
        __syncthreads();
    }

    float linv[2][4];
    #pragma unroll
    for (int cg = 0; cg < 2; cg++)
        #pragma unroll
        for (int r = 0; r < 4; r++) {
            float lq = __shfl(lfr[cg][0], (lane & 48) | (quad * 4 + r), 64);
            linv[cg][r] = 1.f / lq;
        }
    #pragma unroll
    for (int cg = 0; cg < 2; cg++)
        #pragma unroll
        for (int nt = 0; nt < 4; nt++)
            #pragma unroll
            for (int r = 0; r < 4; r++) {
                const int s = qbase + wv * 32 + cg * 16 + quad * 4 + r;
                ao[((size_t)b * S_LEN + s) * DMODEL + h * HD + nt * 16 + l16] =
                    f2bf(Ofr[cg][nt][r] * linv[cg][r]);
            }
#undef ATTN_STAGE
#undef ATTN_COMPUTE
}

// ---------------------------------------------------------------------------
// K3: out = ao @ w_proj_bf16^T + b_proj.  128x64 tile, ring-3 counted-vmcnt
// (R7 verbatim).
// ---------------------------------------------------------------------------
#define PROJ_STAGE(bi, kk) do { \
    unsigned short* dA_ = smem + (bi) * 6144; \
    unsigned short* dB_ = dA_ + 4096; \
    gload_lds16(ag + (kk),               dA_ + wv * 512); \
    gload_lds16(ag + 64 * DMODEL + (kk), dA_ + 2048 + wv * 512); \
    gload_lds16(bg + (kk),               dB_ + wv * 512); \
} while (0)

#define PROJ_COMPUTE(bi) do { \
    const unsigned short* sA_ = smem + (bi) * 6144; \
    const unsigned short* sB_ = sA_ + 4096; \
    bf16x8 af[4]; \
    _Pragma("unroll") for (int m_ = 0; m_ < 4; m_++) af[m_] = *(const bf16x8*)&sA_[aoff[m_]]; \
    _Pragma("unroll") for (int n_ = 0; n_ < 2; n_++) { \
        bf16x8 bf = *(const bf16x8*)&sB_[boff[n_]]; \
        _Pragma("unroll") for (int m_ = 0; m_ < 4; m_++) \
            acc[m_][n_] = __builtin_amdgcn_mfma_f32_16x16x32_bf16(af[m_], bf, acc[m_][n_], 0, 0, 0); \
    } \
} while (0)

__global__ __launch_bounds__(256, 3) void proj_kernel(
    const unsigned short* __restrict__ a, const unsigned short* __restrict__ wpb,
    const float* __restrict__ bias, float* __restrict__ out)
{
    __shared__ __align__(16) unsigned short smem[18432];

    const int t = threadIdx.x;
    const int v = (blockIdx.x & 7) * 64 + (blockIdx.x >> 3);
    const int mbase = (v >> 4) * 128;
    const int nbase = (v & 15) * 64;
    const int wv = t >> 6, lane = t & 63, quad = lane >> 4, l16 = lane & 15;
    const int wr = wv >> 1, wc = wv & 1;

    floatx4 acc[4][2];
    #pragma unroll
    for (int m = 0; m < 4; m++)
        #pragma unroll
        for (int n = 0; n < 2; n++)
            #pragma unroll
            for (int r = 0; r < 4; r++) acc[m][n][r] = 0.f;

    const int srow = t >> 2;
    const int schunk = (t & 3) ^ SROW(srow);
    const unsigned short* ag = a + (size_t)(mbase + srow) * DMODEL + schunk * 8;
    const unsigned short* bg = wpb + (size_t)(nbase + srow) * DMODEL + schunk * 8;

    const int Sl = SROW(l16);
    int aoff[4], boff[2];
    #pragma unroll
    for (int m = 0; m < 4; m++) aoff[m] = (wr * 64 + m * 16 + l16) * 32 + (quad ^ Sl) * 8;
    #pragma unroll
    for (int n = 0; n < 2; n++) boff[n] = (wc * 32 + n * 16 + l16) * 32 + (quad ^ Sl) * 8;

    PROJ_STAGE(0, 0);
    PROJ_STAGE(1, 32);
    for (int tb = 0; tb < 30; tb += 3) {
        WAITV_BAR(3); PROJ_STAGE(2, (tb + 2) * 32); PROJ_COMPUTE(0);
        WAITV_BAR(3); PROJ_STAGE(0, (tb + 3) * 32); PROJ_COMPUTE(1);
        WAITV_BAR(3); PROJ_STAGE(1, (tb + 4) * 32); PROJ_COMPUTE(2);
    }
    WAITV_BAR(3); PROJ_COMPUTE(0);   // tile 30
    WAITV_BAR(0); PROJ_COMPUTE(1);   // tile 31

    #pragma unroll
    for (int n = 0; n < 2; n++) {
        const int nn = nbase + wc * 32 + n * 16 + l16;
        const float bvv = bias[nn];
        #pragma unroll
        for (int m = 0; m < 4; m++)
            #pragma unroll
            for (int r = 0; r < 4; r++)
                out[(size_t)(mbase + wr * 64 + m * 16 + quad * 4 + r) * DMODEL + nn] =
                    acc[m][n][r] + bvv;
    }
}

extern "C" void kernel_launch(void* const* d_in, const int* in_sizes, int n_in,
                              void* d_out, int out_size, void* d_ws, size_t ws_size,
                              hipStream_t stream) {
    const float* x      = (const float*)d_in[0];
    const float* freqs  = (const float*)d_in[2];
    const float* w_qkv  = (const float*)d_in[3];
    const float* b_qkv  = (const float*)d_in[4];
    const float* w_proj = (const float*)d_in[5];
    const float* b_proj = (const float*)d_in[6];
    float* out = (float*)d_out;

    unsigned short* ws = (unsigned short*)d_ws;
    const size_t HSZ = (size_t)2 * NH * S_LEN * HD;   // 4,194,304 shorts
    unsigned short* qb  = ws;
    unsigned short* kb  = ws + HSZ;
    unsigned short* vb  = ws + 2 * HSZ;
    unsigned short* ao  = ws + 3 * HSZ;
    unsigned short* xb  = ws + 4 * HSZ;                       // 4096x1024 bf16
    unsigned short* wqb = xb + (size_t)4096 * 1024;           // 3072x1024 bf16
    unsigned short* wpb = wqb + (size_t)3072 * 1024;          // 1024x1024 bf16
    float2* cs = (float2*)(wpb + (size_t)1024 * 1024);        // 2048x32 (cos,sin)

    prep_kernel<<<2048, 256, 0, stream>>>(x, w_qkv, w_proj, freqs, xb, wqb, wpb, cs);
    qkv_gemm_kernel<<<768, 256, 0, stream>>>(xb, wqb, b_qkv, cs, qb, kb, vb);
    attn_kernel<<<512, 256, 0, stream>>>(qb, kb, vb, ao);
    proj_kernel<<<512, 256, 0, stream>>>(ao, wpb, b_proj, out);
}